// Round 1
// baseline (343.611 us; speedup 1.0000x reference)
//
#include <hip/hip_runtime.h>
#include <math.h>

#define CHI 64
#define CHO 64
#define KKW 9
#define BB 4
#define HH 128
#define WW 256
#define HWSZ (HH * WW)

// Transposed weights live in module globals -> no dependence on ws_size,
// written by a prep kernel each call (deterministic, graph-capture safe).
__device__ float g_wT[CHI * KKW * CHO];    // [(c*9+k)*64 + o]
__device__ float g_wOffT[CHI * KKW * 27];  // [(c*9+k)*27 + co]

__global__ void prep_transpose(const float* __restrict__ weight,
                               const float* __restrict__ w_off) {
    int idx = blockIdx.x * blockDim.x + threadIdx.x;
    if (idx < CHO * CHI * KKW) {
        int o  = idx / (CHI * KKW);
        int ck = idx % (CHI * KKW);
        g_wT[ck * CHO + o] = weight[idx];
    }
    if (idx < 27 * CHI * KKW) {
        int co = idx / (CHI * KKW);
        int ck = idx % (CHI * KKW);
        g_wOffT[ck * 27 + co] = w_off[idx];
    }
}

// Block = 256 threads: 4 waves, each wave = one output row segment of 64 px.
// grid = (WW/64, HH/4, BB)
__global__ __launch_bounds__(256) void dcn_fused(
    const float* __restrict__ x, const float* __restrict__ b_off,
    const float* __restrict__ bias, float* __restrict__ out)
{
    const int lane = threadIdx.x & 63;
    const int wvid = threadIdx.x >> 6;
    const int w = blockIdx.x * 64 + lane;
    const int h = blockIdx.y * 4 + wvid;
    const int b = blockIdx.z;
    const float* __restrict__ xb = x + (size_t)b * CHI * HWSZ;

    // ---------------- Phase A: 3x3 offset conv -> om[27] ----------------
    float om[27];
#pragma unroll
    for (int i = 0; i < 27; ++i) om[i] = b_off[i];

    for (int c = 0; c < CHI; ++c) {
        const float* __restrict__ xc = xb + c * HWSZ;
#pragma unroll
        for (int ky = 0; ky < 3; ++ky) {
            const int iy = h + ky - 1;
            if (iy < 0 || iy >= HH) continue;   // wave-uniform (h uniform per wave)
            const float* __restrict__ xr = xc + iy * WW;
#pragma unroll
            for (int kx = 0; kx < 3; ++kx) {
                const int ix = w + kx - 1;
                const float xv = (ix >= 0 && ix < WW) ? xr[ix] : 0.f;
                const float* __restrict__ wp = &g_wOffT[(c * 9 + ky * 3 + kx) * 27];
#pragma unroll
                for (int co = 0; co < 27; ++co)
                    om[co] = fmaf(xv, wp[co], om[co]);
            }
        }
    }

    // offsets (y,x interleaved) and sigmoid mask
    float offy[9], offx[9], mwt[9];
#pragma unroll
    for (int k = 0; k < 9; ++k) {
        offy[k] = om[2 * k];
        offx[k] = om[2 * k + 1];
        mwt[k]  = 1.f / (1.f + __expf(-om[18 + k]));
    }

    // ---------------- Phase B: sample + main conv ----------------
    float acc[CHO];
#pragma unroll
    for (int o = 0; o < CHO; ++o) acc[o] = bias[o];

    for (int k = 0; k < 9; ++k) {
        const int ky = k / 3, kx = k % 3;
        const float sy = (float)(h - 1 + ky) + offy[k];
        const float sx = (float)(w - 1 + kx) + offx[k];
        const float fy0 = floorf(sy), fx0 = floorf(sx);
        const int y0 = (int)fy0, x0 = (int)fx0;
        const float dy = sy - fy0, dx = sx - fx0;
        const float m = mwt[k];
        float w00 = (1.f - dy) * (1.f - dx) * m;
        float w01 = (1.f - dy) * dx * m;
        float w10 = dy * (1.f - dx) * m;
        float w11 = dy * dx * m;
        const bool vy0 = (y0 >= 0) & (y0 < HH);
        const bool vy1 = (y0 + 1 >= 0) & (y0 + 1 < HH);
        const bool vx0 = (x0 >= 0) & (x0 < WW);
        const bool vx1 = (x0 + 1 >= 0) & (x0 + 1 < WW);
        const float c00 = (vy0 && vx0) ? w00 : 0.f;
        const float c01 = (vy0 && vx1) ? w01 : 0.f;
        const float c10 = (vy1 && vx0) ? w10 : 0.f;
        const float c11 = (vy1 && vx1) ? w11 : 0.f;
        const int cy0 = min(max(y0, 0), HH - 1);
        const int cy1 = min(max(y0 + 1, 0), HH - 1);
        const int cx0 = min(max(x0, 0), WW - 1);
        const int cx1 = min(max(x0 + 1, 0), WW - 1);
        const int i00 = cy0 * WW + cx0, i01 = cy0 * WW + cx1;
        const int i10 = cy1 * WW + cx0, i11 = cy1 * WW + cx1;

        const float* __restrict__ xc = xb;
        for (int c = 0; c < CHI; ++c, xc += HWSZ) {
            const float s = c00 * xc[i00] + c01 * xc[i01] + c10 * xc[i10] + c11 * xc[i11];
            const float* __restrict__ wp = &g_wT[(c * 9 + k) * CHO];
#pragma unroll
            for (int o = 0; o < CHO; ++o)
                acc[o] = fmaf(s, wp[o], acc[o]);
        }
    }

    float* __restrict__ op = out + ((size_t)b * CHO) * HWSZ + h * WW + w;
#pragma unroll
    for (int o = 0; o < CHO; ++o) op[o * HWSZ] = acc[o];
}

extern "C" void kernel_launch(void* const* d_in, const int* in_sizes, int n_in,
                              void* d_out, int out_size, void* d_ws, size_t ws_size,
                              hipStream_t stream) {
    const float* x      = (const float*)d_in[0];
    const float* w_off  = (const float*)d_in[1];
    const float* b_off  = (const float*)d_in[2];
    const float* weight = (const float*)d_in[3];
    const float* bias   = (const float*)d_in[4];
    float* out = (float*)d_out;

    prep_transpose<<<144, 256, 0, stream>>>(weight, w_off);

    dim3 grid(WW / 64, HH / 4, BB);
    dcn_fused<<<grid, 256, 0, stream>>>(x, b_off, bias, out);
}

// Round 2
// 291.561 us; speedup vs baseline: 1.1785x; 1.1785x over previous
//
#include <hip/hip_runtime.h>
#include <math.h>

#define CHI 64
#define CHO 64
#define BB 4
#define HH 128
#define WW 256
#define HWSZ (HH * WW)     // 32768 px per channel plane
#define KTOT 576           // K = khat*64 + c
#define NSTEP 18           // 576 / 32

typedef float f32x4 __attribute__((ext_vector_type(4)));
typedef short bf16x8 __attribute__((ext_vector_type(8)));

// Transposed bf16 weights in device globals (no ws_size dependence).
__device__ __attribute__((aligned(16))) ushort g_wB[CHO * KTOT];    // [o][khat*64+c]
__device__ __attribute__((aligned(16))) ushort g_wOffB[32 * KTOT];  // [co][khat*64+c], co 27..31 = 0

__device__ __forceinline__ ushort f2bf(float f) {
    uint32_t u = __builtin_bit_cast(uint32_t, f);
    u = (u + 0x7fffu + ((u >> 16) & 1u)) >> 16;   // RNE
    return (ushort)u;
}
__device__ __forceinline__ uint32_t pk2(float a, float b) {
    return (uint32_t)f2bf(a) | ((uint32_t)f2bf(b) << 16);
}
__device__ __forceinline__ float bfl(uint32_t lo16) {
    return __builtin_bit_cast(float, lo16 << 16);
}

__global__ void prep(const float* __restrict__ weight, const float* __restrict__ w_off) {
    int idx = blockIdx.x * 256 + threadIdx.x;
    if (idx < CHO * KTOT) {
        int o = idx / KTOT, K = idx % KTOT, kh = K >> 6, c = K & 63;
        g_wB[idx] = f2bf(weight[(o * CHI + c) * 9 + kh]);
    }
    if (idx < 32 * KTOT) {
        int o = idx / KTOT, K = idx % KTOT, kh = K >> 6, c = K & 63;
        g_wOffB[idx] = (o < 27) ? f2bf(w_off[(o * CHI + c) * 9 + kh]) : (ushort)0;
    }
}

// 256 threads = 4 waves; wave = 16 consecutive px; block = 64 px of one image row chunk.
// grid.x = 131072/64 = 2048 (512 blocks per batch image).
__global__ __launch_bounds__(256) void dcn_mfma(
    const float* __restrict__ x, const float* __restrict__ b_off,
    const float* __restrict__ bias, float* __restrict__ out)
{
    __shared__ float om_lds[4][16][33];   // [wave][px][ch], padded
    __shared__ uint4 pm_lds[4][16][9];    // [wave][px][khat] = {y0|x0<<16, w00|w01, w10|w11, pad}

    const int tid = threadIdx.x;
    const int wv = tid >> 6, l = tid & 63;
    const int lr = l & 15, lg = l >> 4;          // frag row/col index, k-group
    const int blk = blockIdx.x;
    const int b = blk >> 9;                      // 512 blocks per batch
    const int pbase = (blk & 511) * 64 + wv * 16;  // wave's px tile base (within batch)
    const float* __restrict__ xb = x + (size_t)b * CHI * HWSZ;

    // ---------------- Phase 1: offset conv (16px x 27ch) via MFMA ----------------
    {
        const int p = pbase + lr;                 // A-row px for this lane
        const int h = p >> 8, w = p & 255;
        f32x4 acc0 = {0.f, 0.f, 0.f, 0.f}, acc1 = {0.f, 0.f, 0.f, 0.f};
        for (int s = 0; s < NSTEP; ++s) {
            const int kh = s >> 1;
            const int iy = h + (kh / 3) - 1, ix = w + (kh % 3) - 1;
            const bool valid = ((unsigned)iy < HH) & ((unsigned)ix < WW);
            const int idx = valid ? (iy * WW + ix) : 0;
            const int c0 = (s & 1) * 32 + lg * 8;
            union { uint32_t u[4]; bf16x8 v; } A;
#pragma unroll
            for (int jj = 0; jj < 4; ++jj) {
                float f0 = xb[(size_t)(c0 + 2 * jj) * HWSZ + idx];
                float f1 = xb[(size_t)(c0 + 2 * jj + 1) * HWSZ + idx];
                if (!valid) { f0 = 0.f; f1 = 0.f; }
                A.u[jj] = pk2(f0, f1);
            }
            const int koff = s * 32 + lg * 8;
            bf16x8 b0 = *(const bf16x8*)&g_wOffB[(0 * 16 + lr) * KTOT + koff];
            bf16x8 b1 = *(const bf16x8*)&g_wOffB[(16 + lr) * KTOT + koff];
            acc0 = __builtin_amdgcn_mfma_f32_16x16x32_bf16(A.v, b0, acc0, 0, 0, 0);
            acc1 = __builtin_amdgcn_mfma_f32_16x16x32_bf16(A.v, b1, acc1, 0, 0, 0);
        }
        // C layout: col(ch)=lr, row(px)=lg*4+i
#pragma unroll
        for (int i = 0; i < 4; ++i) {
            om_lds[wv][lg * 4 + i][lr]      = acc0[i];
            om_lds[wv][lg * 4 + i][16 + lr] = acc1[i];
        }
    }

    // ---------------- Params: bilinear corners + mask-folded weights ----------------
#pragma unroll
    for (int t = 0; t < 3; ++t) {
        const int kh = lg + t * 4;
        if (kh < 9) {
            const int px = lr;
            const int p2 = pbase + px;
            const int h2 = p2 >> 8, w2 = p2 & 255;
            float offy = om_lds[wv][px][2 * kh]     + b_off[2 * kh];
            float offx = om_lds[wv][px][2 * kh + 1] + b_off[2 * kh + 1];
            float mm   = om_lds[wv][px][18 + kh]    + b_off[18 + kh];
            mm = 1.f / (1.f + __expf(-mm));
            const float sy = (float)(h2 - 1 + kh / 3) + offy;
            const float sx = (float)(w2 - 1 + kh % 3) + offx;
            const float fy = floorf(sy), fx = floorf(sx);
            const int y0 = (int)fy, x0 = (int)fx;
            const float dy = sy - fy, dx = sx - fx;
            const float wy0 = (1.f - dy) * mm, wy1 = dy * mm;
            float w00 = wy0 * (1.f - dx), w01 = wy0 * dx;
            float w10 = wy1 * (1.f - dx), w11 = wy1 * dx;
            const bool vy0 = (unsigned)y0 < HH, vy1 = (unsigned)(y0 + 1) < HH;
            const bool vx0 = (unsigned)x0 < WW, vx1 = (unsigned)(x0 + 1) < WW;
            if (!(vy0 & vx0)) w00 = 0.f;
            if (!(vy0 & vx1)) w01 = 0.f;
            if (!(vy1 & vx0)) w10 = 0.f;
            if (!(vy1 & vx1)) w11 = 0.f;
            const uint32_t u0 = (uint32_t)(uint16_t)(int16_t)y0 |
                                ((uint32_t)(uint16_t)(int16_t)x0 << 16);
            pm_lds[wv][px][kh] = make_uint4(u0, pk2(w00, w01), pk2(w10, w11), 0u);
        }
    }

    // ---------------- Phase 2: main conv (16px x 64ch) via MFMA + gather ----------------
    f32x4 acc[4];
#pragma unroll
    for (int n = 0; n < 4; ++n) acc[n] = (f32x4){0.f, 0.f, 0.f, 0.f};

    uint32_t o00 = 0, o01 = 0, o10 = 0, o11 = 0;
    float w00 = 0.f, w01 = 0.f, w10 = 0.f, w11 = 0.f;

    for (int s = 0; s < NSTEP; ++s) {
        const int kh = s >> 1;
        if ((s & 1) == 0) {
            const uint4 pm = pm_lds[wv][lr][kh];   // broadcast across lane groups
            const int y0 = (int)(short)(pm.x & 0xffffu);
            const int x0 = (int)(short)(pm.x >> 16);
            const int cy0 = min(max(y0, 0), HH - 1), cy1 = min(max(y0 + 1, 0), HH - 1);
            const int cx0 = min(max(x0, 0), WW - 1), cx1 = min(max(x0 + 1, 0), WW - 1);
            o00 = (uint32_t)((cy0 * WW + cx0) * 4);
            o01 = (uint32_t)((cy0 * WW + cx1) * 4);
            o10 = (uint32_t)((cy1 * WW + cx0) * 4);
            o11 = (uint32_t)((cy1 * WW + cx1) * 4);
            w00 = bfl(pm.y & 0xffffu); w01 = bfl(pm.y >> 16);
            w10 = bfl(pm.z & 0xffffu); w11 = bfl(pm.z >> 16);
        }
        const int c0 = (s & 1) * 32 + lg * 8;
        const char* xc = (const char*)xb + (size_t)c0 * HWSZ * 4;
        union { uint32_t u[4]; bf16x8 v; } A;
#pragma unroll
        for (int jj = 0; jj < 4; ++jj) {
            float s0, s1;
            {
                float v00 = *(const float*)(xc + o00), v01 = *(const float*)(xc + o01);
                float v10 = *(const float*)(xc + o10), v11 = *(const float*)(xc + o11);
                s0 = w00 * v00 + w01 * v01 + w10 * v10 + w11 * v11;
            }
            xc += HWSZ * 4;
            {
                float v00 = *(const float*)(xc + o00), v01 = *(const float*)(xc + o01);
                float v10 = *(const float*)(xc + o10), v11 = *(const float*)(xc + o11);
                s1 = w00 * v00 + w01 * v01 + w10 * v10 + w11 * v11;
            }
            xc += HWSZ * 4;
            A.u[jj] = pk2(s0, s1);
        }
        const int koff = s * 32 + lg * 8;
#pragma unroll
        for (int n = 0; n < 4; ++n) {
            bf16x8 bfr = *(const bf16x8*)&g_wB[(n * 16 + lr) * KTOT + koff];
            acc[n] = __builtin_amdgcn_mfma_f32_16x16x32_bf16(A.v, bfr, acc[n], 0, 0, 0);
        }
    }

    // ---------------- Epilogue: C(col=o, row=px) + bias -> out[b][o][px] ----------------
#pragma unroll
    for (int n = 0; n < 4; ++n) {
        const int o = n * 16 + lr;
        const float bo = bias[o];
        float* op = out + ((size_t)b * CHO + o) * HWSZ + pbase + lg * 4;
        f32x4 r;
#pragma unroll
        for (int i = 0; i < 4; ++i) r[i] = acc[n][i] + bo;
        *(f32x4*)op = r;
    }
}

extern "C" void kernel_launch(void* const* d_in, const int* in_sizes, int n_in,
                              void* d_out, int out_size, void* d_ws, size_t ws_size,
                              hipStream_t stream) {
    const float* x      = (const float*)d_in[0];
    const float* w_off  = (const float*)d_in[1];
    const float* b_off  = (const float*)d_in[2];
    const float* weight = (const float*)d_in[3];
    const float* bias   = (const float*)d_in[4];
    float* out = (float*)d_out;

    prep<<<144, 256, 0, stream>>>(weight, w_off);
    dcn_mfma<<<2048, 256, 0, stream>>>(x, b_off, bias, out);
}

// Round 3
// 190.997 us; speedup vs baseline: 1.7990x; 1.5265x over previous
//
#include <hip/hip_runtime.h>
#include <math.h>

#define CHI 64
#define CHO 64
#define BB 4
#define HH 128
#define WW 256
#define HWSZ (HH * WW)     // 32768 px per channel plane
#define KTOT 576           // K = khat*64 + c
#define NSTEP 18           // 576 / 32

typedef float f32x4 __attribute__((ext_vector_type(4)));
typedef short bf16x8 __attribute__((ext_vector_type(8)));

// Device-global staging (no ws_size dependence).
__device__ __attribute__((aligned(16))) ushort g_xT[BB * HWSZ * CHI];  // NHWC bf16: [b*HWSZ+px][c]
__device__ __attribute__((aligned(16))) ushort g_wB[CHO * KTOT];       // [o][khat*64+c]
__device__ __attribute__((aligned(16))) ushort g_wOffB[32 * KTOT];     // [co][khat*64+c], co 27..31 = 0

__device__ __forceinline__ ushort f2bf(float f) {
    uint32_t u = __builtin_bit_cast(uint32_t, f);
    u = (u + 0x7fffu + ((u >> 16) & 1u)) >> 16;   // RNE
    return (ushort)u;
}
__device__ __forceinline__ uint32_t pk2(float a, float b) {
    return (uint32_t)f2bf(a) | ((uint32_t)f2bf(b) << 16);
}
__device__ __forceinline__ float bflo(uint32_t u) { return __builtin_bit_cast(float, u << 16); }
__device__ __forceinline__ float bfhi(uint32_t u) { return __builtin_bit_cast(float, u & 0xffff0000u); }
__device__ __forceinline__ uint32_t cvtpk(float lo, float hi) {
    uint32_t r;
    asm("v_cvt_pk_bf16_f32 %0, %1, %2" : "=v"(r) : "v"(lo), "v"(hi));
    return r;
}

__global__ void prep(const float* __restrict__ weight, const float* __restrict__ w_off) {
    int idx = blockIdx.x * 256 + threadIdx.x;
    if (idx < CHO * KTOT) {
        int o = idx / KTOT, K = idx % KTOT, kh = K >> 6, c = K & 63;
        g_wB[idx] = f2bf(weight[(o * CHI + c) * 9 + kh]);
    }
    if (idx < 32 * KTOT) {
        int o = idx / KTOT, K = idx % KTOT, kh = K >> 6, c = K & 63;
        g_wOffB[idx] = (o < 27) ? f2bf(w_off[(o * CHI + c) * 9 + kh]) : (ushort)0;
    }
}

// NCHW f32 -> NHWC bf16 transpose. Block = 64 px x 64 ch tile.
__global__ __launch_bounds__(256) void transform(const float* __restrict__ x) {
    __shared__ ushort t[64][68];   // pad 68: 136B row stride -> 2-way bank (free), 8B-aligned rows
    const int tid = threadIdx.x;
    const int wv = tid >> 6, lane = tid & 63;
    const int pb = blockIdx.x * 64;          // global px index base (includes batch)
    const int b = pb >> 15;
    const int pin = pb & (HWSZ - 1);
    const float* __restrict__ xb = x + (size_t)b * CHI * HWSZ + pin;
#pragma unroll
    for (int i = 0; i < 16; ++i) {
        const int c = wv * 16 + i;
        t[lane][c] = f2bf(xb[(size_t)c * HWSZ + lane]);
    }
    __syncthreads();
    // thread -> px = tid>>2, 16 channels starting at (tid&3)*16
    const int px = tid >> 2, cb = (tid & 3) * 16;
    const uint32_t* __restrict__ row = (const uint32_t*)&t[px][cb];
    uint4 v0, v1;
    v0.x = row[0]; v0.y = row[1]; v0.z = row[2]; v0.w = row[3];
    v1.x = row[4]; v1.y = row[5]; v1.z = row[6]; v1.w = row[7];
    uint4* __restrict__ dst = (uint4*)&g_xT[(size_t)(pb + px) * CHI + cb];
    dst[0] = v0; dst[1] = v1;
}

// 256 threads = 4 waves; wave = 16 consecutive px; block = 64 px.
__global__ __launch_bounds__(256) void dcn_mfma(
    const float* __restrict__ b_off, const float* __restrict__ bias,
    float* __restrict__ out)
{
    __shared__ float om_lds[4][16][33];    // [wave][px][ch]
    __shared__ uint4 po_lds[4][16][9];     // corner byte offsets {o00,o01,o10,o11} (within batch)
    __shared__ uint2 pw_lds[4][16][9];     // packed bf16 corner weights {w00|w01, w10|w11}

    const int tid = threadIdx.x;
    const int wv = tid >> 6, l = tid & 63;
    const int lr = l & 15, lg = l >> 4;
    const int blk = blockIdx.x;
    const int b = blk >> 9;
    const int pbase = (blk & 511) * 64 + wv * 16;
    const char* __restrict__ xtb = (const char*)g_xT + (size_t)b * HWSZ * (CHI * 2);

    // ---------------- Phase 1: offset conv (16px x 27ch) via MFMA ----------------
    {
        const int p = pbase + lr;
        const int h = p >> 8, w = p & 255;
        f32x4 acc0 = {0.f, 0.f, 0.f, 0.f}, acc1 = {0.f, 0.f, 0.f, 0.f};
        for (int s = 0; s < NSTEP; ++s) {
            const int kh = s >> 1;
            const int iy = h + (kh / 3) - 1, ix = w + (kh % 3) - 1;
            const bool valid = ((unsigned)iy < HH) & ((unsigned)ix < WW);
            const int pidx = valid ? (iy * WW + ix) : 0;
            const int c0 = (s & 1) * 32 + lg * 8;
            union { uint32_t u[4]; bf16x8 v; } A;
            A.v = *(const bf16x8*)(xtb + (size_t)pidx * (CHI * 2) + c0 * 2);
            if (!valid) { A.u[0] = 0; A.u[1] = 0; A.u[2] = 0; A.u[3] = 0; }
            const int koff = s * 32 + lg * 8;
            bf16x8 b0 = *(const bf16x8*)&g_wOffB[(size_t)lr * KTOT + koff];
            bf16x8 b1 = *(const bf16x8*)&g_wOffB[(size_t)(16 + lr) * KTOT + koff];
            acc0 = __builtin_amdgcn_mfma_f32_16x16x32_bf16(A.v, b0, acc0, 0, 0, 0);
            acc1 = __builtin_amdgcn_mfma_f32_16x16x32_bf16(A.v, b1, acc1, 0, 0, 0);
        }
#pragma unroll
        for (int i = 0; i < 4; ++i) {
            om_lds[wv][lg * 4 + i][lr]      = acc0[i];
            om_lds[wv][lg * 4 + i][16 + lr] = acc1[i];
        }
    }
    __syncthreads();

    // ---------------- Params: corner offsets + mask-folded bf16 weights ----------------
#pragma unroll
    for (int t = 0; t < 3; ++t) {
        const int kh = lg + t * 4;
        if (kh < 9) {
            const int px = lr;
            const int p2 = pbase + px;
            const int h2 = p2 >> 8, w2 = p2 & 255;
            float offy = om_lds[wv][px][2 * kh]     + b_off[2 * kh];
            float offx = om_lds[wv][px][2 * kh + 1] + b_off[2 * kh + 1];
            float mm   = om_lds[wv][px][18 + kh]    + b_off[18 + kh];
            mm = 1.f / (1.f + __expf(-mm));
            const float sy = (float)(h2 - 1 + kh / 3) + offy;
            const float sx = (float)(w2 - 1 + kh % 3) + offx;
            const float fy = floorf(sy), fx = floorf(sx);
            const int y0 = (int)fy, x0 = (int)fx;
            const float dy = sy - fy, dx = sx - fx;
            const float wy0 = (1.f - dy) * mm, wy1 = dy * mm;
            float w00 = wy0 * (1.f - dx), w01 = wy0 * dx;
            float w10 = wy1 * (1.f - dx), w11 = wy1 * dx;
            const bool vy0 = (unsigned)y0 < HH, vy1 = (unsigned)(y0 + 1) < HH;
            const bool vx0 = (unsigned)x0 < WW, vx1 = (unsigned)(x0 + 1) < WW;
            if (!(vy0 & vx0)) w00 = 0.f;
            if (!(vy0 & vx1)) w01 = 0.f;
            if (!(vy1 & vx0)) w10 = 0.f;
            if (!(vy1 & vx1)) w11 = 0.f;
            const int cy0 = min(max(y0, 0), HH - 1), cy1 = min(max(y0 + 1, 0), HH - 1);
            const int cx0 = min(max(x0, 0), WW - 1), cx1 = min(max(x0 + 1, 0), WW - 1);
            po_lds[wv][px][kh] = make_uint4(
                (uint32_t)((cy0 * WW + cx0) * (CHI * 2)),
                (uint32_t)((cy0 * WW + cx1) * (CHI * 2)),
                (uint32_t)((cy1 * WW + cx0) * (CHI * 2)),
                (uint32_t)((cy1 * WW + cx1) * (CHI * 2)));
            pw_lds[wv][px][kh] = make_uint2(pk2(w00, w01), pk2(w10, w11));
        }
    }
    __syncthreads();

    // ---------------- Phase 2: gather-bilerp (vectorized) + MFMA ----------------
    f32x4 acc[4];
#pragma unroll
    for (int n = 0; n < 4; ++n) acc[n] = (f32x4){0.f, 0.f, 0.f, 0.f};

    uint4 po = {0, 0, 0, 0};
    float w00 = 0.f, w01 = 0.f, w10 = 0.f, w11 = 0.f;

    for (int s = 0; s < NSTEP; ++s) {
        const int kh = s >> 1;
        if ((s & 1) == 0) {
            po = po_lds[wv][lr][kh];
            const uint2 pw = pw_lds[wv][lr][kh];
            w00 = bflo(pw.x); w01 = bfhi(pw.x);
            w10 = bflo(pw.y); w11 = bfhi(pw.y);
        }
        const int c0 = (s & 1) * 32 + lg * 8;
        const char* __restrict__ xc = xtb + c0 * 2;
        union { uint32_t u[4]; bf16x8 v; } C00, C01, C10, C11, A;
        C00.v = *(const bf16x8*)(xc + po.x);
        C01.v = *(const bf16x8*)(xc + po.y);
        C10.v = *(const bf16x8*)(xc + po.z);
        C11.v = *(const bf16x8*)(xc + po.w);
#pragma unroll
        for (int j = 0; j < 4; ++j) {
            float se = w00 * bflo(C00.u[j]);
            se = fmaf(w01, bflo(C01.u[j]), se);
            se = fmaf(w10, bflo(C10.u[j]), se);
            se = fmaf(w11, bflo(C11.u[j]), se);
            float so = w00 * bfhi(C00.u[j]);
            so = fmaf(w01, bfhi(C01.u[j]), so);
            so = fmaf(w10, bfhi(C10.u[j]), so);
            so = fmaf(w11, bfhi(C11.u[j]), so);
            A.u[j] = cvtpk(se, so);
        }
        const int koff = s * 32 + lg * 8;
#pragma unroll
        for (int n = 0; n < 4; ++n) {
            bf16x8 bfr = *(const bf16x8*)&g_wB[(size_t)(n * 16 + lr) * KTOT + koff];
            acc[n] = __builtin_amdgcn_mfma_f32_16x16x32_bf16(A.v, bfr, acc[n], 0, 0, 0);
        }
    }

    // ---------------- Epilogue ----------------
#pragma unroll
    for (int n = 0; n < 4; ++n) {
        const int o = n * 16 + lr;
        const float bo = bias[o];
        float* op = out + ((size_t)b * CHO + o) * HWSZ + pbase + lg * 4;
        f32x4 r;
#pragma unroll
        for (int i = 0; i < 4; ++i) r[i] = acc[n][i] + bo;
        *(f32x4*)op = r;
    }
}

extern "C" void kernel_launch(void* const* d_in, const int* in_sizes, int n_in,
                              void* d_out, int out_size, void* d_ws, size_t ws_size,
                              hipStream_t stream) {
    const float* x      = (const float*)d_in[0];
    const float* w_off  = (const float*)d_in[1];
    const float* b_off  = (const float*)d_in[2];
    const float* weight = (const float*)d_in[3];
    const float* bias   = (const float*)d_in[4];
    float* out = (float*)d_out;

    prep<<<144, 256, 0, stream>>>(weight, w_off);
    transform<<<2048, 256, 0, stream>>>(x);
    dcn_mfma<<<2048, 256, 0, stream>>>(b_off, bias, out);
}